// Round 17
// baseline (569.174 us; speedup 1.0000x reference)
//
#include <hip/hip_runtime.h>

// ---------------------------------------------------------------------------
// GLMAttention: qkv proj (+RoPE) -> fused flash attn (scores out + softmax+PV)
// -> output proj.  All matmuls fp16 MFMA (16x16x32), f32 accumulate.
// B=4 S=1024 HID=2048 H=16 D=128.
// Round 17: flash = BARRIER-FREE WAVE-PRIVATE PIPELINE. Each wave owns a
// private double-buffered K/V LDS slice (BT=32, 32KB/wave, 128KB/block,
// 1 block/CU). No s_barrier anywhere: per iter, wave issues streams(t+1) +
// gll16(t+1) into spare buffer, waits vmcnt(24) (retires tile t staging by
// exact count), computes t. Waves drift out of phase -> no phase-lock.
// P exchange in-register (r10), V swizzle per r8.
// ---------------------------------------------------------------------------

#define B_  4
#define S_  1024
#define HID_ 2048
#define H_  16
#define D_  128
#define RSQRT_D 0.08838834764831845f

typedef _Float16 f16x8 __attribute__((ext_vector_type(8)));
typedef _Float16 f16x4 __attribute__((ext_vector_type(4)));
typedef float f32x4 __attribute__((ext_vector_type(4)));
typedef unsigned int u32x2 __attribute__((ext_vector_type(2)));
typedef unsigned int u32x4 __attribute__((ext_vector_type(4)));

#define MFMA16(a, b, c) __builtin_amdgcn_mfma_f32_16x16x32_f16(a, b, c, 0, 0, 0)

__device__ __forceinline__ void gll16(const void* g, void* l) {
  __builtin_amdgcn_global_load_lds(
      (const __attribute__((address_space(1))) void*)g,
      (__attribute__((address_space(3))) void*)l, 16, 0, 0);
}

// ---------------------------------------------------------------------------
// Merged f32 -> f16 convert for all 7 tensors + RoPE tables.
// ---------------------------------------------------------------------------
__global__ __launch_bounds__(256) void cvt_all_kernel(
    const float* __restrict__ w0, const float* __restrict__ w1,
    const float* __restrict__ w2, const float* __restrict__ w3,
    const float* __restrict__ x0, const float* __restrict__ x1,
    const float* __restrict__ x2,
    _Float16* __restrict__ dw0, _Float16* __restrict__ dw1,
    _Float16* __restrict__ dw2, _Float16* __restrict__ dw3,
    _Float16* __restrict__ dx0, _Float16* __restrict__ dx1,
    _Float16* __restrict__ dx2,
    float* __restrict__ tcos, float* __restrict__ tsin) {
  if (blockIdx.x >= 20480) {  // RoPE tables: 32768 entries
    const int i = (blockIdx.x - 20480) * 256 + threadIdx.x;
    const int pos = i >> 5, j = i & 31;
    const float inv = expf(-(float)j * (9.210340371976184f / 32.0f));
    const float ang = (float)pos * inv;
    tcos[i] = cosf(ang);
    tsin[i] = sinf(ang);
    return;
  }
  const int i = blockIdx.x * blockDim.x + threadIdx.x;  // unit index
  const float* src;
  _Float16* dst;
  int off;
  if (i < 2097152) {                 // weights: 4 x 524288
    const int seg = i >> 19;
    off = i & 524287;
    src = (seg == 0) ? w0 : (seg == 1) ? w1 : (seg == 2) ? w2 : w3;
    dst = (seg == 0) ? dw0 : (seg == 1) ? dw1 : (seg == 2) ? dw2 : dw3;
  } else {                           // X: 3 x 1048576
    const int j = i - 2097152;
    const int seg = j >> 20;
    off = j & 1048575;
    src = (seg == 0) ? x0 : (seg == 1) ? x1 : x2;
    dst = (seg == 0) ? dx0 : (seg == 1) ? dx1 : dx2;
  }
  const f32x4* in4 = (const f32x4*)src;
  f32x4 a = in4[(size_t)off * 2], b = in4[(size_t)off * 2 + 1];
  f16x8 v;
  v[0] = (_Float16)a[0]; v[1] = (_Float16)a[1]; v[2] = (_Float16)a[2]; v[3] = (_Float16)a[3];
  v[4] = (_Float16)b[0]; v[5] = (_Float16)b[1]; v[6] = (_Float16)b[2]; v[7] = (_Float16)b[3];
  *(f16x8*)(dst + (size_t)off * 8) = v;
}

// ---------------------------------------------------------------------------
// Fused Q/K/V projection: one 1536-block launch, 512 blocks per segment.
// ---------------------------------------------------------------------------
__global__ __launch_bounds__(256) void proj_qkv_kernel(
    const _Float16* __restrict__ Xq, const _Float16* __restrict__ Xk,
    const _Float16* __restrict__ Xv,
    const _Float16* __restrict__ Wq, const _Float16* __restrict__ Wk,
    const _Float16* __restrict__ Wv,
    const float* __restrict__ bq, const float* __restrict__ bk,
    const float* __restrict__ bv,
    _Float16* __restrict__ oq, _Float16* __restrict__ ok,
    _Float16* __restrict__ ovt,
    const int* __restrict__ pids, const float* __restrict__ tcos,
    const float* __restrict__ tsin) {
  constexpr int N = HID_, K = HID_;
  constexpr int BK = 64;
  __shared__ _Float16 As[128 * BK];
  __shared__ _Float16 Bs[128 * BK];

  const int tid = threadIdx.x;
  const int gbid = (blockIdx.x & 7) * 192 + (blockIdx.x >> 3);
  const int seg = gbid >> 9;          // 0=q, 1=k, 2=v (block-uniform)
  const int bid = gbid & 511;
  const _Float16* A  = (seg == 0) ? Xq : (seg == 1) ? Xk : Xv;
  const _Float16* Bw = (seg == 0) ? Wq : (seg == 1) ? Wk : Wv;
  const float*  bias = (seg == 0) ? bq : (seg == 1) ? bk : bv;

  const int tm = bid >> 4, tn = bid & 15;  // 32 x 16 tiles
  const int m0 = tm * 128, n0 = tn * 128;
  const int w = tid >> 6, l = tid & 63;
  const int mw = (w >> 1) * 64, nw = (w & 1) * 64;
  const int lr = l & 15, lh = l >> 4;

  f32x4 acc[4][4] = {};

  for (int kt = 0; kt < K / BK; ++kt) {
    const int k0 = kt * BK;
    __syncthreads();
#pragma unroll
    for (int i = 0; i < 4; ++i) {
      const int e = i * 2048 + tid * 8;
      gll16(A + (size_t)(m0 + (e >> 6)) * K + k0 + (e & 63), As + e);
      gll16(Bw + (size_t)(n0 + (e >> 6)) * K + k0 + (e & 63), Bs + e);
    }
    asm volatile("s_waitcnt vmcnt(0)" ::: "memory");
    __syncthreads();
#pragma unroll
    for (int kk = 0; kk < 2; ++kk) {
      f16x8 af[4], bf[4];
#pragma unroll
      for (int mi = 0; mi < 4; ++mi)
        af[mi] = *(const f16x8*)(As + (mw + mi * 16 + lr) * BK + kk * 32 + lh * 8);
#pragma unroll
      for (int ni = 0; ni < 4; ++ni)
        bf[ni] = *(const f16x8*)(Bs + (nw + ni * 16 + lr) * BK + kk * 32 + lh * 8);
#pragma unroll
      for (int mi = 0; mi < 4; ++mi)
#pragma unroll
        for (int ni = 0; ni < 4; ++ni)
          acc[mi][ni] = MFMA16(af[mi], bf[ni], acc[mi][ni]);
    }
  }

  if (seg == 2) {  // V: write (B,H,D,S) directly
    _Float16* out = ovt;
#pragma unroll
    for (int mi = 0; mi < 4; ++mi)
#pragma unroll
      for (int ni = 0; ni < 4; ++ni) {
        const int col = n0 + nw + ni * 16 + lr;
        const float bb = bias[col];
        const int h = col >> 7, hd = col & 127;
#pragma unroll
        for (int r = 0; r < 4; ++r) {
          const int row = m0 + mw + mi * 16 + lh * 4 + r;
          const int b = row >> 10, s = row & 1023;
          out[(((size_t)(b * H_ + h)) * D_ + hd) * S_ + s] = (_Float16)(acc[mi][ni][r] + bb);
        }
      }
  } else {  // q/k: RoPE epilogue
    _Float16* out = (seg == 0) ? oq : ok;
    const int sel = (nw >> 6) & 1;
#pragma unroll
    for (int mi = 0; mi < 4; ++mi) {
#pragma unroll
      for (int r = 0; r < 4; ++r) {
        const int row = m0 + mw + mi * 16 + lh * 4 + r;
        const int b = row >> 10, s = row & 1023;
        const int pos = pids[b * 2 * S_ + sel * S_ + s];
#pragma unroll
        for (int ni = 0; ni < 2; ++ni) {
          const int col = n0 + nw + ni * 16 + lr;
          const int j = ni * 16 + lr;
          const float c = tcos[pos * 32 + j];
          const float sn = tsin[pos * 32 + j];
          const float x1 = acc[mi][ni][r] + bias[col];
          const float x2 = acc[mi][ni + 2][r] + bias[col + 32];
          const int h = col >> 7, hd = col & 127;
          const size_t base = (((size_t)(b * H_ + h)) * S_ + s) * D_;
          out[base + hd] = (_Float16)(x1 * c - x2 * sn);
          out[base + hd + 32] = (_Float16)(x2 * c + x1 * sn);
        }
      }
    }
  }
}

// ---------------------------------------------------------------------------
// Final projection: C = ctx @ Wo^T + bo -> f32 (M,N).
// ---------------------------------------------------------------------------
__global__ __launch_bounds__(256) void proj_out_kernel(
    const _Float16* __restrict__ A, const _Float16* __restrict__ Bw,
    const float* __restrict__ bias, float* __restrict__ out) {
  constexpr int N = HID_, K = HID_;
  constexpr int BK = 64;
  __shared__ _Float16 As[128 * BK];
  __shared__ _Float16 Bs[128 * BK];

  const int tid = threadIdx.x;
  const int bid = (blockIdx.x & 7) * 64 + (blockIdx.x >> 3);
  const int tm = bid >> 4, tn = bid & 15;
  const int m0 = tm * 128, n0 = tn * 128;
  const int w = tid >> 6, l = tid & 63;
  const int mw = (w >> 1) * 64, nw = (w & 1) * 64;
  const int lr = l & 15, lh = l >> 4;

  f32x4 acc[4][4] = {};

  for (int kt = 0; kt < K / BK; ++kt) {
    const int k0 = kt * BK;
    __syncthreads();
#pragma unroll
    for (int i = 0; i < 4; ++i) {
      const int e = i * 2048 + tid * 8;
      gll16(A + (size_t)(m0 + (e >> 6)) * K + k0 + (e & 63), As + e);
      gll16(Bw + (size_t)(n0 + (e >> 6)) * K + k0 + (e & 63), Bs + e);
    }
    asm volatile("s_waitcnt vmcnt(0)" ::: "memory");
    __syncthreads();
#pragma unroll
    for (int kk = 0; kk < 2; ++kk) {
      f16x8 af[4], bf[4];
#pragma unroll
      for (int mi = 0; mi < 4; ++mi)
        af[mi] = *(const f16x8*)(As + (mw + mi * 16 + lr) * BK + kk * 32 + lh * 8);
#pragma unroll
      for (int ni = 0; ni < 4; ++ni)
        bf[ni] = *(const f16x8*)(Bs + (nw + ni * 16 + lr) * BK + kk * 32 + lh * 8);
#pragma unroll
      for (int mi = 0; mi < 4; ++mi)
#pragma unroll
        for (int ni = 0; ni < 4; ++ni)
          acc[mi][ni] = MFMA16(af[mi], bf[ni], acc[mi][ni]);
    }
  }

#pragma unroll
  for (int mi = 0; mi < 4; ++mi)
#pragma unroll
    for (int ni = 0; ni < 4; ++ni) {
      const int col = n0 + nw + ni * 16 + lr;
      const float bb = bias[col];
#pragma unroll
      for (int r = 0; r < 4; ++r) {
        const int row = m0 + mw + mi * 16 + lh * 4 + r;
        out[(size_t)row * N + col] = acc[mi][ni][r] + bb;
      }
    }
}

// ---------------------------------------------------------------------------
// Fused flash attention, BARRIER-FREE wave-private pipeline, BT=32.
// Block = (b,h, 64 q-rows); 4 waves x 16 rows; each wave owns a private
// double-buffered K/V LDS slice (32 KB/wave). Per iter: issue streams(t+1),
// issue staging(t+1) into spare buffer, s_waitcnt vmcnt(24) (retires
// staging(t): newer ops = 2 stores + 6 streams + 16 gll16), sched_barrier,
// compute(t). NO s_barrier / __syncthreads in the loop.
// ---------------------------------------------------------------------------
__global__ __launch_bounds__(256) void flash_kernel(
    const _Float16* __restrict__ q, const _Float16* __restrict__ k,
    const _Float16* __restrict__ vt, const float* __restrict__ pbias,
    const float* __restrict__ maskp, const float* __restrict__ prev,
    float* __restrict__ scores, _Float16* __restrict__ ctx) {
  constexpr int BT = 32;
  __shared__ _Float16 KsAll[4][2][BT * D_];   // 4 waves x 2 bufs x 8 KB = 64 KB
  __shared__ _Float16 VTsAll[4][2][D_ * BT];  // 64 KB   (total 128 KB)

  const int tid = threadIdx.x, w = tid >> 6, l = tid & 63;
  const int lr = l & 15, lh = l >> 4;
  // XCD swizzle: 1024 blocks -> 128 consecutive per XCD (8 planes/XCD)
  const int sid = (blockIdx.x & 7) * 128 + (blockIdx.x >> 3);
  const int qt = sid & 15, byh = sid >> 4;
  const int b = byh >> 4, h = byh & 15;
  const size_t plane = (size_t)byh;
  const int q0 = qt * 64 + w * 16;
  const int qrow = q0 + lr;           // this lane's q-row
  const int swz = (lr & 7) << 3;      // K frag-read XOR

  // P-exchange lane indices (r10 verified; 4-lane group, stride 16)
  const int srcA = lr + ((l & 16) << 1);  // lr + 32*(lh&1)
  const int srcB = srcA + 16;
  const bool selHi = (l & 32) != 0;       // lh>>1

  const float* prow  = prev  + (plane * S_ + qrow) * S_;
  const float* pbrow = pbias + ((size_t)h * S_ + qrow) * S_;
  const float* mrow  = maskp + ((size_t)b * S_ + qrow) * S_;
  float*       srow  = scores + (plane * S_ + qrow) * S_;
  const _Float16* kpl = k  + plane * S_ * D_;
  const _Float16* vpl = vt + plane * D_ * S_;

  // Q B-fragments: lane provides Q[row=lr][k]
  f16x8 qa[4];
#pragma unroll
  for (int kk = 0; kk < 4; ++kk)
    qa[kk] = *(const f16x8*)(q + (plane * S_ + qrow) * D_ + kk * 32 + lh * 8);

  f32x4 o[8] = {};
  float m_r = -1e30f, l_r = 0.0f;

  _Float16* kA = &KsAll[w][0][0];
  _Float16* kB = &KsAll[w][1][0];
  _Float16* vA = &VTsAll[w][0][0];
  _Float16* vB = &VTsAll[w][1][0];

  // prologue: streams(0) + stage tile 0 into A (wave-private, 16 gll16)
  f32x4 pvA[2], pbA[2], mkA[2];
#pragma unroll
  for (int nt = 0; nt < 2; ++nt) {
    const int toff = nt * 16 + lh * 4;
    pvA[nt] = *(const f32x4*)(prow + toff);
    pbA[nt] = *(const f32x4*)(pbrow + toff);
    mkA[nt] = *(const f32x4*)(mrow + toff);
  }
#pragma unroll
  for (int i = 0; i < 8; ++i) {
    const int e = i * 512 + l * 8;
    const int krow = e >> 7;
    gll16(kpl + (size_t)krow * D_ + ((e & 127) ^ ((krow & 7) << 3)), kA + e);
    const int vrow = e >> 5;
    gll16(vpl + (size_t)vrow * S_ + ((e & 31) ^ (((vrow >> 1) & 3) << 3)), vA + e);
  }
  asm volatile("s_waitcnt vmcnt(0)" ::: "memory");
  __builtin_amdgcn_sched_barrier(0);

  for (int tt = 0; tt < S_ / BT; ++tt) {
    const int t0 = tt * BT;
    const int t1 = (tt < S_ / BT - 1) ? t0 + BT : 0;  // tail wraps (unused)

    // A: streams(t+1) -> B register set (6 loads)
    f32x4 pvB[2], pbB[2], mkB[2];
#pragma unroll
    for (int nt = 0; nt < 2; ++nt) {
      const int toff = t1 + nt * 16 + lh * 4;
      pvB[nt] = *(const f32x4*)(prow + toff);
      pbB[nt] = *(const f32x4*)(pbrow + toff);
      mkB[nt] = *(const f32x4*)(mrow + toff);
    }
    // B: stage(t+1) into spare buffer (16 gll16, wave-private, always issued)
#pragma unroll
    for (int i = 0; i < 8; ++i) {
      const int e = i * 512 + l * 8;
      const int krow = e >> 7;
      gll16(kpl + (size_t)(t1 + krow) * D_ + ((e & 127) ^ ((krow & 7) << 3)), kB + e);
      const int vrow = e >> 5;
      gll16(vpl + (size_t)vrow * S_ + t1 + ((e & 31) ^ (((vrow >> 1) & 3) << 3)), vB + e);
    }
    // C: retire staging(t).  Newer ops: stores(t-1)=2 + streams(t+1)=6 +
    //    staging(t+1)=16 -> wait vmcnt(24). Wave-local; no barrier.
    asm volatile("s_waitcnt vmcnt(24)" ::: "memory");
    __builtin_amdgcn_sched_barrier(0);

    // D: QK^T swapped from private bufA: sa[nt][r]=S[t0+nt*16+lh*4+r][qrow]
    f32x4 sa[2] = {};
    __builtin_amdgcn_s_setprio(1);
#pragma unroll
    for (int nt = 0; nt < 2; ++nt)
#pragma unroll
      for (int kk = 0; kk < 4; ++kk) {
        const int row = nt * 16 + lr;
        f16x8 kb = *(const f16x8*)(kA + row * D_ + ((kk * 32 + lh * 8) ^ swz));
        sa[nt] = MFMA16(kb, qa[kk], sa[nt]);
      }
    __builtin_amdgcn_s_setprio(0);

    // epilogue: registers only + 2 stores
#pragma unroll
    for (int nt = 0; nt < 2; ++nt) {
      const int toff = t0 + nt * 16 + lh * 4;
      f32x4 sc4 = (sa[nt] + pbA[nt]) * RSQRT_D + mkA[nt] + pvA[nt];
      *(f32x4*)(srow + toff) = sc4;
      sa[nt] = sc4;
    }

    // online softmax (8 values), row group = lanes {l, l^16, l^32, l^48}
    float tmx = fmaxf(fmaxf(fmaxf(sa[0][0], sa[0][1]), fmaxf(sa[0][2], sa[0][3])),
                      fmaxf(fmaxf(sa[1][0], sa[1][1]), fmaxf(sa[1][2], sa[1][3])));
    tmx = fmaxf(tmx, __shfl_xor(tmx, 16));
    tmx = fmaxf(tmx, __shfl_xor(tmx, 32));
    if (!__all(tmx <= m_r + 8.0f)) {   // T13 defer-max
      const float newm = fmaxf(m_r, tmx);
      const float al = __expf(m_r - newm);
      m_r = newm;
      l_r *= al;
#pragma unroll
      for (int nd = 0; nd < 8; ++nd) o[nd] *= al;
    }
    float ts = 0.0f;
#pragma unroll
    for (int nt = 0; nt < 2; ++nt)
#pragma unroll
      for (int r = 0; r < 4; ++r) {
        const float pe = __expf(sa[nt][r] - m_r);
        sa[nt][r] = pe;
        ts += pe;
      }
    ts += __shfl_xor(ts, 16);
    ts += __shfl_xor(ts, 32);
    l_r += ts;

    // ---- P redistribution in-register (r10, single kk2) ----
    unsigned int u0w0, u0w1, u1w0, u1w1;
    {
      f16x4 pk0, pk1;
#pragma unroll
      for (int r = 0; r < 4; ++r) { pk0[r] = (_Float16)sa[0][r]; pk1[r] = (_Float16)sa[1][r]; }
      u32x2 v0 = __builtin_bit_cast(u32x2, pk0); u0w0 = v0[0]; u0w1 = v0[1];
      u32x2 v1 = __builtin_bit_cast(u32x2, pk1); u1w0 = v1[0]; u1w1 = v1[1];
    }
    const unsigned a00 = (unsigned)__shfl((int)u0w0, srcA), a01 = (unsigned)__shfl((int)u0w1, srcA);
    const unsigned a10 = (unsigned)__shfl((int)u1w0, srcA), a11 = (unsigned)__shfl((int)u1w1, srcA);
    const unsigned b00 = (unsigned)__shfl((int)u0w0, srcB), b01 = (unsigned)__shfl((int)u0w1, srcB);
    const unsigned b10 = (unsigned)__shfl((int)u1w0, srcB), b11 = (unsigned)__shfl((int)u1w1, srcB);
    u32x4 paw;
    paw[0] = selHi ? a10 : a00; paw[1] = selHi ? a11 : a01;
    paw[2] = selHi ? b10 : b00; paw[3] = selHi ? b11 : b01;
    const f16x8 pa = __builtin_bit_cast(f16x8, paw);

    // PV swapped from private bufA: o[nd][r] = ctx[d=nd*16+lh*4+r][qrow]
    __builtin_amdgcn_s_setprio(1);
#pragma unroll
    for (int nd = 0; nd < 8; ++nd) {
      const int vr = nd * 16 + lr;
      const f16x8 vb = *(const f16x8*)(vA + vr * BT + ((lh * 8) ^ (((vr >> 1) & 3) << 3)));
      o[nd] = MFMA16(vb, pa, o[nd]);
    }
    __builtin_amdgcn_s_setprio(0);

    // swap private buffers + rotate stream registers (no barrier!)
    _Float16* tp;
    tp = kA; kA = kB; kB = tp;
    tp = vA; vA = vB; vB = tp;
#pragma unroll
    for (int nt = 0; nt < 2; ++nt) {
      pvA[nt] = pvB[nt]; pbA[nt] = pbB[nt]; mkA[nt] = mkB[nt];
    }
  }

  // ctx write: lane owns q-row qrow, d = nd*16 + lh*4 + r -> f16x4 stores
  const float inv_l = 1.0f / l_r;
  _Float16* crow = ctx + ((size_t)(b * S_) + qrow) * HID_ + h * D_;
#pragma unroll
  for (int nd = 0; nd < 8; ++nd) {
    f16x4 cv;
#pragma unroll
    for (int r = 0; r < 4; ++r) cv[r] = (_Float16)(o[nd][r] * inv_l);
    *(f16x4*)(crow + nd * 16 + lh * 4) = cv;
  }
}

// ---------------------------------------------------------------------------
extern "C" void kernel_launch(void* const* d_in, const int* in_sizes, int n_in,
                              void* d_out, int out_size, void* d_ws, size_t ws_size,
                              hipStream_t stream) {
  const float* query = (const float*)d_in[0];
  const float* key_i = (const float*)d_in[1];
  const float* value = (const float*)d_in[2];
  const float* maskp = (const float*)d_in[3];
  const float* pbias = (const float*)d_in[4];
  const float* prev  = (const float*)d_in[5];
  const int*   pids  = (const int*)d_in[6];
  const float* Wq = (const float*)d_in[7];
  const float* bq = (const float*)d_in[8];
  const float* Wk = (const float*)d_in[9];
  const float* bk = (const float*)d_in[10];
  const float* Wv = (const float*)d_in[11];
  const float* bv = (const float*)d_in[12];
  const float* Wo = (const float*)d_in[13];
  const float* bo = (const float*)d_in[14];

  char* ws = (char*)d_ws;
  const size_t OFF_TCOS = 0;
  const size_t OFF_TSIN = 131072;
  const size_t OFF_W    = 262144;                      // 4 x 8 MB f16 weights
  const size_t OFF_X    = OFF_W + 4ull * 8388608;      // 3 x 16 MB f16 X
  const size_t OFF_Q    = OFF_X + 3ull * 16777216;
  const size_t OFF_K    = OFF_Q + 16777216;
  const size_t OFF_VT   = OFF_K + 16777216;            // V proj writes here (B,H,D,S)
  const size_t OFF_CTX  = OFF_X + 16777216;            // reuse Xk (consumed)

  float* tcos = (float*)(ws + OFF_TCOS);
  float* tsin = (float*)(ws + OFF_TSIN);
  _Float16* Wq16 = (_Float16*)(ws + OFF_W);
  _Float16* Wk16 = (_Float16*)(ws + OFF_W + 8388608);
  _Float16* Wv16 = (_Float16*)(ws + OFF_W + 2ull * 8388608);
  _Float16* Wo16 = (_Float16*)(ws + OFF_W + 3ull * 8388608);
  _Float16* Xq16 = (_Float16*)(ws + OFF_X);
  _Float16* Xk16 = (_Float16*)(ws + OFF_X + 16777216);
  _Float16* Xv16 = (_Float16*)(ws + OFF_X + 2ull * 16777216);
  _Float16* q16  = (_Float16*)(ws + OFF_Q);
  _Float16* k16  = (_Float16*)(ws + OFF_K);
  _Float16* vt16 = (_Float16*)(ws + OFF_VT);
  _Float16* ctx16 = (_Float16*)(ws + OFF_CTX);

  float* out_f32 = (float*)d_out;                 // (B,S,HID) = 8,388,608
  float* scores  = (float*)d_out + 8388608;       // (B,H,S,S) = 67,108,864

  cvt_all_kernel<<<20608, 256, 0, stream>>>(Wq, Wk, Wv, Wo, query, key_i, value,
                                            Wq16, Wk16, Wv16, Wo16,
                                            Xq16, Xk16, Xv16, tcos, tsin);

  proj_qkv_kernel<<<1536, 256, 0, stream>>>(Xq16, Xk16, Xv16,
                                            Wq16, Wk16, Wv16,
                                            bq, bk, bv,
                                            q16, k16, vt16,
                                            pids, tcos, tsin);

  flash_kernel<<<1024, 256, 0, stream>>>(q16, k16, vt16, pbias, maskp, prev,
                                         scores, ctx16);

  proj_out_kernel<<<512, 256, 0, stream>>>(ctx16, Wo16, bo, out_f32);
}

// Round 18
// 441.516 us; speedup vs baseline: 1.2891x; 1.2891x over previous
//
#include <hip/hip_runtime.h>

// ---------------------------------------------------------------------------
// GLMAttention: qkv proj (+RoPE) -> fused flash attn (scores out + softmax+PV)
// -> output proj.  All matmuls fp16 MFMA (16x16x32), f32 accumulate.
// B=4 S=1024 HID=2048 H=16 D=128.
// Round 18: flash reverted to r14 best (211us). proj_qkv ported to the
// 8-phase 256^2 template (T3+T4): 512 thr / 8 waves (2Mx4N), BK=64, 128KB
// dbuf LDS, counted vmcnt(8) (stage tile j+1 in phase 0 of tile j; wait
// retires tile j's staging, keeps 8 loads in flight), per-phase barriers +
// lgkmcnt(0)+sched_barrier + setprio around 16-MFMA clusters, swizzled LDS
// (col ^ ((row&7)<<3)) via pre-swizzled gll16 source. proj_out stays 128^2.
// ---------------------------------------------------------------------------

#define B_  4
#define S_  1024
#define HID_ 2048
#define H_  16
#define D_  128
#define RSQRT_D 0.08838834764831845f

typedef _Float16 f16x8 __attribute__((ext_vector_type(8)));
typedef _Float16 f16x4 __attribute__((ext_vector_type(4)));
typedef float f32x4 __attribute__((ext_vector_type(4)));

#define MFMA16(a, b, c) __builtin_amdgcn_mfma_f32_16x16x32_f16(a, b, c, 0, 0, 0)

__device__ __forceinline__ void gll16(const void* g, void* l) {
  __builtin_amdgcn_global_load_lds(
      (const __attribute__((address_space(1))) void*)g,
      (__attribute__((address_space(3))) void*)l, 16, 0, 0);
}

// ---------------------------------------------------------------------------
// Merged f32 -> f16 convert for all 7 tensors + RoPE tables.
// ---------------------------------------------------------------------------
__global__ __launch_bounds__(256) void cvt_all_kernel(
    const float* __restrict__ w0, const float* __restrict__ w1,
    const float* __restrict__ w2, const float* __restrict__ w3,
    const float* __restrict__ x0, const float* __restrict__ x1,
    const float* __restrict__ x2,
    _Float16* __restrict__ dw0, _Float16* __restrict__ dw1,
    _Float16* __restrict__ dw2, _Float16* __restrict__ dw3,
    _Float16* __restrict__ dx0, _Float16* __restrict__ dx1,
    _Float16* __restrict__ dx2,
    float* __restrict__ tcos, float* __restrict__ tsin) {
  if (blockIdx.x >= 20480) {  // RoPE tables: 32768 entries
    const int i = (blockIdx.x - 20480) * 256 + threadIdx.x;
    const int pos = i >> 5, j = i & 31;
    const float inv = expf(-(float)j * (9.210340371976184f / 32.0f));
    const float ang = (float)pos * inv;
    tcos[i] = cosf(ang);
    tsin[i] = sinf(ang);
    return;
  }
  const int i = blockIdx.x * blockDim.x + threadIdx.x;  // unit index
  const float* src;
  _Float16* dst;
  int off;
  if (i < 2097152) {                 // weights: 4 x 524288
    const int seg = i >> 19;
    off = i & 524287;
    src = (seg == 0) ? w0 : (seg == 1) ? w1 : (seg == 2) ? w2 : w3;
    dst = (seg == 0) ? dw0 : (seg == 1) ? dw1 : (seg == 2) ? dw2 : dw3;
  } else {                           // X: 3 x 1048576
    const int j = i - 2097152;
    const int seg = j >> 20;
    off = j & 1048575;
    src = (seg == 0) ? x0 : (seg == 1) ? x1 : x2;
    dst = (seg == 0) ? dx0 : (seg == 1) ? dx1 : dx2;
  }
  const f32x4* in4 = (const f32x4*)src;
  f32x4 a = in4[(size_t)off * 2], b = in4[(size_t)off * 2 + 1];
  f16x8 v;
  v[0] = (_Float16)a[0]; v[1] = (_Float16)a[1]; v[2] = (_Float16)a[2]; v[3] = (_Float16)a[3];
  v[4] = (_Float16)b[0]; v[5] = (_Float16)b[1]; v[6] = (_Float16)b[2]; v[7] = (_Float16)b[3];
  *(f16x8*)(dst + (size_t)off * 8) = v;
}

// ---------------------------------------------------------------------------
// Fused Q/K/V projection, 8-phase 256x256 template.
// Grid 384 (3 segs x 16x8 tiles of 256). 512 threads = 8 waves (2M x 4N);
// per-wave output 128x64 (8 mi x 4 ni frags). BK=64, NK=32 K-tiles.
// Per tile j: phase0 { stage(j+1) -> vmcnt(8) -> barrier -> q0 },
// phases 1-3 { barrier -> ds_read q -> lgkmcnt(0) -> 16 MFMA }, trailing
// barrier (reads done -> next staging safe). Quadrant p: qm=p&1, kk=p>>1.
// ---------------------------------------------------------------------------
__device__ __forceinline__ void stage_tile_256(
    const _Float16* __restrict__ A, const _Float16* __restrict__ Bw,
    int m0, int n0, int k0s, _Float16* ad, _Float16* bd, int tid) {
#pragma unroll
  for (int i = 0; i < 4; ++i) {
    const int e = i * 4096 + tid * 8;
    const int rrow = e >> 6;
    const int rcol = (e & 63) ^ ((rrow & 7) << 3);
    gll16(A + (size_t)(m0 + rrow) * HID_ + k0s + rcol, ad + e);
    gll16(Bw + (size_t)(n0 + rrow) * HID_ + k0s + rcol, bd + e);
  }
}

__global__ __launch_bounds__(512) void proj_qkv_kernel(
    const _Float16* __restrict__ Xq, const _Float16* __restrict__ Xk,
    const _Float16* __restrict__ Xv,
    const _Float16* __restrict__ Wq, const _Float16* __restrict__ Wk,
    const _Float16* __restrict__ Wv,
    const float* __restrict__ bq, const float* __restrict__ bk,
    const float* __restrict__ bv,
    _Float16* __restrict__ oq, _Float16* __restrict__ ok,
    _Float16* __restrict__ ovt,
    const int* __restrict__ pids, const float* __restrict__ tcos,
    const float* __restrict__ tsin) {
  constexpr int K = HID_;
  constexpr int BK = 64;
  constexpr int NK = K / BK;             // 32
  __shared__ _Float16 As[2][256 * BK];   // 64 KB
  __shared__ _Float16 Bs[2][256 * BK];   // 64 KB

  const int tid = threadIdx.x;
  // XCD swizzle over 384 blocks (384 % 8 == 0 -> bijective)
  const int gbid = (blockIdx.x & 7) * 48 + (blockIdx.x >> 3);
  const int seg = gbid / 128;            // 0=q,1=k,2=v (block-uniform)
  const int bid = gbid % 128;
  const _Float16* A  = (seg == 0) ? Xq : (seg == 1) ? Xk : Xv;
  const _Float16* Bw = (seg == 0) ? Wq : (seg == 1) ? Wk : Wv;
  const float*  bias = (seg == 0) ? bq : (seg == 1) ? bk : bv;

  const int tm = bid >> 3, tn = bid & 7; // 16 x 8 tiles
  const int m0 = tm * 256, n0 = tn * 256;
  const int w = tid >> 6, l = tid & 63;
  const int wr = w >> 2, wc = w & 3;     // 2M x 4N waves
  const int lr = l & 15, lh = l >> 4;
  const int swz = (lr & 7) << 3;

  f32x4 acc[8][4] = {};

  // prologue: stage tile 0 into buf 0
  stage_tile_256(A, Bw, m0, n0, 0, &As[0][0], &Bs[0][0], tid);

  for (int j = 0; j < NK; ++j) {
    const _Float16* as = &As[j & 1][0];
    const _Float16* bs = &Bs[j & 1][0];

    // phase 0 head: stage next tile, counted wait, visibility barrier
    if (j + 1 < NK) {
      stage_tile_256(A, Bw, m0, n0, (j + 1) * BK,
                     &As[(j + 1) & 1][0], &Bs[(j + 1) & 1][0], tid);
      asm volatile("s_waitcnt vmcnt(8)" ::: "memory");   // retire tile j's 8
    } else {
      asm volatile("s_waitcnt vmcnt(0)" ::: "memory");
    }
    __builtin_amdgcn_sched_barrier(0);
    __builtin_amdgcn_s_barrier();

#pragma unroll
    for (int p = 0; p < 4; ++p) {
      const int qm = p & 1, kk = p >> 1;
      if (p > 0) __builtin_amdgcn_s_barrier();
      f16x8 af[4], bf[4];
#pragma unroll
      for (int i = 0; i < 4; ++i)
        af[i] = *(const f16x8*)(as + (wr * 128 + (qm * 4 + i) * 16 + lr) * BK +
                                ((kk * 32 + lh * 8) ^ swz));
#pragma unroll
      for (int ni = 0; ni < 4; ++ni)
        bf[ni] = *(const f16x8*)(bs + (wc * 64 + ni * 16 + lr) * BK +
                                 ((kk * 32 + lh * 8) ^ swz));
      asm volatile("s_waitcnt lgkmcnt(0)" ::: "memory");
      __builtin_amdgcn_sched_barrier(0);
      __builtin_amdgcn_s_setprio(1);
#pragma unroll
      for (int i = 0; i < 4; ++i)
#pragma unroll
        for (int ni = 0; ni < 4; ++ni)
          acc[qm * 4 + i][ni] = MFMA16(af[i], bf[ni], acc[qm * 4 + i][ni]);
      __builtin_amdgcn_s_setprio(0);
    }
    // trailing barrier: every wave's lgkmcnt(0) preceded this -> all reads of
    // buf[j&1] complete -> next iteration's staging overwrite is safe.
    __builtin_amdgcn_s_barrier();
  }

  if (seg == 2) {  // V: write (B,H,D,S) directly
#pragma unroll
    for (int mi = 0; mi < 8; ++mi)
#pragma unroll
      for (int ni = 0; ni < 4; ++ni) {
        const int col = n0 + wc * 64 + ni * 16 + lr;
        const float bb = bias[col];
        const int h = col >> 7, hd = col & 127;
#pragma unroll
        for (int r = 0; r < 4; ++r) {
          const int row = m0 + wr * 128 + mi * 16 + lh * 4 + r;
          const int b = row >> 10, s = row & 1023;
          ovt[(((size_t)(b * H_ + h)) * D_ + hd) * S_ + s] =
              (_Float16)(acc[mi][ni][r] + bb);
        }
      }
  } else {  // q/k: RoPE epilogue; wave's 64-col span = one half-head
    _Float16* out = (seg == 0) ? oq : ok;
    const int sel = wc & 1;  // 0 -> pid row, 1 -> bid row of position_ids
#pragma unroll
    for (int mi = 0; mi < 8; ++mi) {
#pragma unroll
      for (int r = 0; r < 4; ++r) {
        const int row = m0 + wr * 128 + mi * 16 + lh * 4 + r;
        const int b = row >> 10, s = row & 1023;
        const int pos = pids[b * 2 * S_ + sel * S_ + s];
#pragma unroll
        for (int ni = 0; ni < 2; ++ni) {
          const int col = n0 + wc * 64 + ni * 16 + lr;  // first of (d, d+32)
          const int jf = ni * 16 + lr;                  // 0..31 freq index
          const float c = tcos[pos * 32 + jf];
          const float sn = tsin[pos * 32 + jf];
          const float x1 = acc[mi][ni][r] + bias[col];
          const float x2 = acc[mi][ni + 2][r] + bias[col + 32];
          const int h = col >> 7, hd = col & 127;
          const size_t base = (((size_t)(b * H_ + h)) * S_ + s) * D_;
          out[base + hd] = (_Float16)(x1 * c - x2 * sn);
          out[base + hd + 32] = (_Float16)(x2 * c + x1 * sn);
        }
      }
    }
  }
}

// ---------------------------------------------------------------------------
// Final projection: C = ctx @ Wo^T + bo -> f32 (M,N).  128^2 tile (512
// blocks = 2 perfect scheduling rounds; 256^2 would halve grid efficiency).
// ---------------------------------------------------------------------------
__global__ __launch_bounds__(256) void proj_out_kernel(
    const _Float16* __restrict__ A, const _Float16* __restrict__ Bw,
    const float* __restrict__ bias, float* __restrict__ out) {
  constexpr int N = HID_, K = HID_;
  constexpr int BK = 64;
  __shared__ _Float16 As[128 * BK];
  __shared__ _Float16 Bs[128 * BK];

  const int tid = threadIdx.x;
  const int bid = (blockIdx.x & 7) * 64 + (blockIdx.x >> 3);
  const int tm = bid >> 4, tn = bid & 15;
  const int m0 = tm * 128, n0 = tn * 128;
  const int w = tid >> 6, l = tid & 63;
  const int mw = (w >> 1) * 64, nw = (w & 1) * 64;
  const int lr = l & 15, lh = l >> 4;

  f32x4 acc[4][4] = {};

  for (int kt = 0; kt < K / BK; ++kt) {
    const int k0 = kt * BK;
    __syncthreads();
#pragma unroll
    for (int i = 0; i < 4; ++i) {
      const int e = i * 2048 + tid * 8;
      gll16(A + (size_t)(m0 + (e >> 6)) * K + k0 + (e & 63), As + e);
      gll16(Bw + (size_t)(n0 + (e >> 6)) * K + k0 + (e & 63), Bs + e);
    }
    asm volatile("s_waitcnt vmcnt(0)" ::: "memory");
    __syncthreads();
#pragma unroll
    for (int kk = 0; kk < 2; ++kk) {
      f16x8 af[4], bf[4];
#pragma unroll
      for (int mi = 0; mi < 4; ++mi)
        af[mi] = *(const f16x8*)(As + (mw + mi * 16 + lr) * BK + kk * 32 + lh * 8);
#pragma unroll
      for (int ni = 0; ni < 4; ++ni)
        bf[ni] = *(const f16x8*)(Bs + (nw + ni * 16 + lr) * BK + kk * 32 + lh * 8);
#pragma unroll
      for (int mi = 0; mi < 4; ++mi)
#pragma unroll
        for (int ni = 0; ni < 4; ++ni)
          acc[mi][ni] = MFMA16(af[mi], bf[ni], acc[mi][ni]);
    }
  }

#pragma unroll
  for (int mi = 0; mi < 4; ++mi)
#pragma unroll
    for (int ni = 0; ni < 4; ++ni) {
      const int col = n0 + nw + ni * 16 + lr;
      const float bb = bias[col];
#pragma unroll
      for (int r = 0; r < 4; ++r) {
        const int row = m0 + mw + mi * 16 + lh * 4 + r;
        out[(size_t)row * N + col] = acc[mi][ni][r] + bb;
      }
    }
}

// ---------------------------------------------------------------------------
// Fused flash attention (r14 best: 2-phase dbuf, BT=64, 4 waves, P-LDS,
// loop-end vmcnt(4) + raw s_barrier leaving the 4 scores stores in flight).
// ---------------------------------------------------------------------------
__global__ __launch_bounds__(256) void flash_kernel(
    const _Float16* __restrict__ q, const _Float16* __restrict__ k,
    const _Float16* __restrict__ vt, const float* __restrict__ pbias,
    const float* __restrict__ maskp, const float* __restrict__ prev,
    float* __restrict__ scores, _Float16* __restrict__ ctx) {
  constexpr int BT = 64;
  __shared__ _Float16 KsBuf[2][BT * D_];   // [t][d] swizzled, 2 x 16 KB
  __shared__ _Float16 VTsBuf[2][D_ * BT];  // [d][t] swizzled, 2 x 16 KB
  __shared__ _Float16 Ps[4][16 * BT];      // per-wave [q][t] swizzled, 8 KB

  const int tid = threadIdx.x, w = tid >> 6, l = tid & 63;
  const int lr = l & 15, lh = l >> 4;
  const int sid = (blockIdx.x & 7) * 128 + (blockIdx.x >> 3);
  const int qt = sid & 15, byh = sid >> 4;
  const int b = byh >> 4, h = byh & 15;
  const size_t plane = (size_t)byh;
  const int q0 = qt * 64 + w * 16;
  const int qrow = q0 + lr;
  const int swz = (lr & 7) << 3;

  const float* prow  = prev  + (plane * S_ + qrow) * S_;
  const float* pbrow = pbias + ((size_t)h * S_ + qrow) * S_;
  const float* mrow  = maskp + ((size_t)b * S_ + qrow) * S_;
  float*       srow  = scores + (plane * S_ + qrow) * S_;
  const _Float16* kpl = k  + plane * S_ * D_;
  const _Float16* vpl = vt + plane * D_ * S_;

  f16x8 qa[4];
#pragma unroll
  for (int kk = 0; kk < 4; ++kk)
    qa[kk] = *(const f16x8*)(q + (plane * S_ + qrow) * D_ + kk * 32 + lh * 8);

  f32x4 o[8] = {};
  float m_r = -1e30f, l_r = 0.0f;

  _Float16* ksA = &KsBuf[0][0];
  _Float16* ksB = &KsBuf[1][0];
  _Float16* vtA = &VTsBuf[0][0];
  _Float16* vtB = &VTsBuf[1][0];

#pragma unroll
  for (int i = 0; i < 4; ++i) {
    const int e = i * 2048 + tid * 8;
    const int krow = e >> 7;
    gll16(kpl + (size_t)krow * D_ + ((e & 127) ^ ((krow & 7) << 3)), ksA + e);
    const int vrow = e >> 6;
    gll16(vpl + (size_t)vrow * S_ + ((e & 63) ^ ((vrow & 7) << 3)), vtA + e);
  }
  __syncthreads();

  for (int tt = 0; tt < S_ / BT; ++tt) {
    const int t0 = tt * BT;

    f32x4 pv4[4], pb4[4], mk4[4];
#pragma unroll
    for (int nt = 0; nt < 4; ++nt) {
      const int toff = t0 + nt * 16 + lh * 4;
      pv4[nt] = __builtin_nontemporal_load((const f32x4*)(prow + toff));
      pb4[nt] = *(const f32x4*)(pbrow + toff);
      mk4[nt] = *(const f32x4*)(mrow + toff);
    }
    if (tt < S_ / BT - 1) {
      const int t1 = t0 + BT;
#pragma unroll
      for (int i = 0; i < 4; ++i) {
        const int e = i * 2048 + tid * 8;
        const int krow = e >> 7;
        gll16(kpl + (size_t)(t1 + krow) * D_ + ((e & 127) ^ ((krow & 7) << 3)), ksB + e);
        const int vrow = e >> 6;
        gll16(vpl + (size_t)vrow * S_ + t1 + ((e & 63) ^ ((vrow & 7) << 3)), vtB + e);
      }
    }

    f32x4 sa[4] = {};
    __builtin_amdgcn_s_setprio(1);
#pragma unroll
    for (int nt = 0; nt < 4; ++nt)
#pragma unroll
      for (int kk = 0; kk < 4; ++kk) {
        const int row = nt * 16 + lr;
        f16x8 kb = *(const f16x8*)(ksA + row * D_ + ((kk * 32 + lh * 8) ^ swz));
        sa[nt] = MFMA16(kb, qa[kk], sa[nt]);
      }
    __builtin_amdgcn_s_setprio(0);

#pragma unroll
    for (int nt = 0; nt < 4; ++nt) {
      const int toff = t0 + nt * 16 + lh * 4;
      f32x4 sc4 = (sa[nt] + pb4[nt]) * RSQRT_D + mk4[nt] + pv4[nt];
      __builtin_nontemporal_store(sc4, (f32x4*)(srow + toff));
      sa[nt] = sc4;
    }

    float tmx = -1e30f;
#pragma unroll
    for (int nt = 0; nt < 4; ++nt)
#pragma unroll
      for (int r = 0; r < 4; ++r) tmx = fmaxf(tmx, sa[nt][r]);
    tmx = fmaxf(tmx, __shfl_xor(tmx, 16));
    tmx = fmaxf(tmx, __shfl_xor(tmx, 32));
    if (!__all(tmx <= m_r + 8.0f)) {   // T13 defer-max
      const float newm = fmaxf(m_r, tmx);
      const float al = __expf(m_r - newm);
      m_r = newm;
      l_r *= al;
#pragma unroll
      for (int nd = 0; nd < 8; ++nd) o[nd] *= al;
    }
    float ts = 0.0f;
#pragma unroll
    for (int nt = 0; nt < 4; ++nt)
#pragma unroll
      for (int r = 0; r < 4; ++r) {
        const float pe = __expf(sa[nt][r] - m_r);
        sa[nt][r] = pe;
        ts += pe;
      }
    ts += __shfl_xor(ts, 16);
    ts += __shfl_xor(ts, 32);
    l_r += ts;

    _Float16* pw = &Ps[w][0];
#pragma unroll
    for (int nt = 0; nt < 4; ++nt) {
      f16x4 pk;
      pk[0] = (_Float16)sa[nt][0]; pk[1] = (_Float16)sa[nt][1];
      pk[2] = (_Float16)sa[nt][2]; pk[3] = (_Float16)sa[nt][3];
      *(f16x4*)(pw + lr * BT + ((nt * 16 + lh * 4) ^ swz)) = pk;
    }

    __builtin_amdgcn_s_setprio(1);
#pragma unroll
    for (int kk2 = 0; kk2 < 2; ++kk2) {
      const f16x8 pa = *(const f16x8*)(pw + lr * BT + ((kk2 * 32 + lh * 8) ^ swz));
#pragma unroll
      for (int nd = 0; nd < 8; ++nd) {
        const int vr = nd * 16 + lr;
        const f16x8 vb = *(const f16x8*)(vtA + vr * BT + ((kk2 * 32 + lh * 8) ^ swz));
        o[nd] = MFMA16(vb, pa, o[nd]);
      }
    }
    __builtin_amdgcn_s_setprio(0);

    asm volatile("s_waitcnt vmcnt(4)" ::: "memory");
    __builtin_amdgcn_s_barrier();
    _Float16* t1p = ksA; ksA = ksB; ksB = t1p;
    _Float16* t2p = vtA; vtA = vtB; vtB = t2p;
  }

  const float inv_l = 1.0f / l_r;
  _Float16* crow = ctx + ((size_t)(b * S_) + qrow) * HID_ + h * D_;
#pragma unroll
  for (int nd = 0; nd < 8; ++nd) {
    f16x4 cv;
#pragma unroll
    for (int r = 0; r < 4; ++r) cv[r] = (_Float16)(o[nd][r] * inv_l);
    *(f16x4*)(crow + nd * 16 + lh * 4) = cv;
  }
}

// ---------------------------------------------------------------------------
extern "C" void kernel_launch(void* const* d_in, const int* in_sizes, int n_in,
                              void* d_out, int out_size, void* d_ws, size_t ws_size,
                              hipStream_t stream) {
  const float* query = (const float*)d_in[0];
  const float* key_i = (const float*)d_in[1];
  const float* value = (const float*)d_in[2];
  const float* maskp = (const float*)d_in[3];
  const float* pbias = (const float*)d_in[4];
  const float* prev  = (const float*)d_in[5];
  const int*   pids  = (const int*)d_in[6];
  const float* Wq = (const float*)d_in[7];
  const float* bq = (const float*)d_in[8];
  const float* Wk = (const float*)d_in[9];
  const float* bk = (const float*)d_in[10];
  const float* Wv = (const float*)d_in[11];
  const float* bv = (const float*)d_in[12];
  const float* Wo = (const float*)d_in[13];
  const float* bo = (const float*)d_in[14];

  char* ws = (char*)d_ws;
  const size_t OFF_TCOS = 0;
  const size_t OFF_TSIN = 131072;
  const size_t OFF_W    = 262144;                      // 4 x 8 MB f16 weights
  const size_t OFF_X    = OFF_W + 4ull * 8388608;      // 3 x 16 MB f16 X
  const size_t OFF_Q    = OFF_X + 3ull * 16777216;
  const size_t OFF_K    = OFF_Q + 16777216;
  const size_t OFF_VT   = OFF_K + 16777216;            // V proj writes (B,H,D,S)
  const size_t OFF_CTX  = OFF_X + 16777216;            // reuse Xk (consumed)

  float* tcos = (float*)(ws + OFF_TCOS);
  float* tsin = (float*)(ws + OFF_TSIN);
  _Float16* Wq16 = (_Float16*)(ws + OFF_W);
  _Float16* Wk16 = (_Float16*)(ws + OFF_W + 8388608);
  _Float16* Wv16 = (_Float16*)(ws + OFF_W + 2ull * 8388608);
  _Float16* Wo16 = (_Float16*)(ws + OFF_W + 3ull * 8388608);
  _Float16* Xq16 = (_Float16*)(ws + OFF_X);
  _Float16* Xk16 = (_Float16*)(ws + OFF_X + 16777216);
  _Float16* Xv16 = (_Float16*)(ws + OFF_X + 2ull * 16777216);
  _Float16* q16  = (_Float16*)(ws + OFF_Q);
  _Float16* k16  = (_Float16*)(ws + OFF_K);
  _Float16* vt16 = (_Float16*)(ws + OFF_VT);
  _Float16* ctx16 = (_Float16*)(ws + OFF_CTX);

  float* out_f32 = (float*)d_out;                 // (B,S,HID) = 8,388,608
  float* scores  = (float*)d_out + 8388608;       // (B,H,S,S) = 67,108,864

  cvt_all_kernel<<<20608, 256, 0, stream>>>(Wq, Wk, Wv, Wo, query, key_i, value,
                                            Wq16, Wk16, Wv16, Wo16,
                                            Xq16, Xk16, Xv16, tcos, tsin);

  // fused Q/K/V projections: 8-phase 256^2, 384 blocks x 512 threads
  proj_qkv_kernel<<<384, 512, 0, stream>>>(Xq16, Xk16, Xv16,
                                           Wq16, Wk16, Wv16,
                                           bq, bk, bv,
                                           q16, k16, vt16,
                                           pids, tcos, tsin);

  flash_kernel<<<1024, 256, 0, stream>>>(q16, k16, vt16, pbias, maskp, prev,
                                         scores, ctx16);

  proj_out_kernel<<<512, 256, 0, stream>>>(ctx16, Wo16, bo, out_f32);
}